// Round 21
// baseline (148.296 us; speedup 1.0000x reference)
//
#include <hip/hip_runtime.h>
#include <hip/hip_bf16.h>
#include <cstdint>

typedef __bf16 bf16x8 __attribute__((ext_vector_type(8)));
typedef float f32x4 __attribute__((ext_vector_type(4)));
typedef float f32x16 __attribute__((ext_vector_type(16)));

// ---------------- async global->LDS (16B per lane) ----------------
__device__ __forceinline__ void gld16(const __bf16* g, __bf16* lds) {
    __builtin_amdgcn_global_load_lds(
        (__attribute__((address_space(1))) void*)(uintptr_t)g,
        (__attribute__((address_space(3))) void*)(uint32_t)(uintptr_t)lds,
        16, 0, 0);
}

// ---------------- fused weight prep: T(Wq1), T(Wq2), encoder pack — one launch ----------------
__global__ __launch_bounds__(256) void prep_all(const float* __restrict__ Wq1, const float* __restrict__ Wq2,
                                                const float* __restrict__ Wp1, const float* __restrict__ bp1,
                                                const float* __restrict__ Wp2, const float* __restrict__ bp2,
                                                const float* __restrict__ Wt1, const float* __restrict__ bt1,
                                                const float* __restrict__ Wt2, const float* __restrict__ bt2,
                                                const float* __restrict__ Wr1, const float* __restrict__ br1,
                                                const float* __restrict__ Wr2, const float* __restrict__ br2,
                                                __bf16* __restrict__ w1t, __bf16* __restrict__ w2t,
                                                float* __restrict__ w1p, __bf16* __restrict__ w2e) {
    __shared__ float t[64][65];
    const int idx = blockIdx.x, tid = threadIdx.x;
    if (idx < 800) {
        const float* in; __bf16* out; int R, C, bx, by;
        if (idx < 672) { in = Wq1; out = w1t; R = 2688; C = 1024; bx = idx % 42; by = idx / 42; }
        else { const int i2 = idx - 672; in = Wq2; out = w2t; R = 1024; C = 512; bx = i2 % 16; by = i2 / 16; }
        const int r0 = bx * 64, c0 = by * 64;
#pragma unroll
        for (int i = 0; i < 16; i++) {
            int id2 = i * 256 + tid;
            int rr = id2 >> 6, cc = id2 & 63;
            t[rr][cc] = in[(size_t)(r0 + rr) * C + (c0 + cc)];
        }
        __syncthreads();
#pragma unroll
        for (int i = 0; i < 16; i++) {
            int id2 = i * 256 + tid;
            int rr = id2 >> 6, cc = id2 & 63;
            out[(size_t)(c0 + rr) * R + (r0 + cc)] = (__bf16)t[cc][rr];
        }
    } else {
        const int s = idx - 800;
        int ks, din, w1off;
        const float *W1, *B1, *W2, *B2;
        if (s < 9)      { ks = s;      din = 5;  w1off = s * 160;
                          W1 = Wp1; B1 = bp1; W2 = Wp2; B2 = bp2; }
        else if (s < 11){ ks = s - 9;  din = 12; w1off = 1440 + ks * 384;
                          W1 = Wt1; B1 = bt1; W2 = Wt2; B2 = bt2; }
        else            { ks = s - 11; din = 9;  w1off = 2208 + ks * 288;
                          W1 = Wr1; B1 = br1; W2 = Wr2; B2 = br2; }
        W1 += ks * din * 32; B1 += ks * 32; W2 += ks * 2048; B2 += ks * 64;
        for (int i = tid; i < din * 32; i += 256) w1p[w1off + i] = W1[i];
        if (tid < 32) w1p[3072 + s * 32 + tid] = B1[tid];
        if (tid < 64) w1p[3520 + s * 64 + tid] = B2[tid];
        for (int i = tid; i < 2048; i += 256) {
            const int o = i >> 5, k = i & 31;
            w2e[s * 2048 + i] = (__bf16)W2[k * 64 + o];
        }
    }
}

// ---------------- fused encoder v3: w2t prefetch pipeline + b128 stores via LDS ----------------
__global__ __launch_bounds__(256) void enc_fused(const float* __restrict__ obs,
                                                 const float* __restrict__ act,
                                                 const float* __restrict__ w1p,
                                                 const __bf16* __restrict__ w2t,
                                                 __bf16* __restrict__ enc) {
    __shared__ float sW[4416];
    __shared__ __bf16 sH[2][64 * 40];
    __shared__ __align__(16) __bf16 sO[2][64 * 72];
    const int tid = threadIdx.x;
    for (int i = tid; i < 4416; i += 256) sW[i] = w1p[i];
    const int rloc = tid >> 2, q = tid & 3;
    const int row = blockIdx.x * 64 + rloc;
    const float* orow = obs + (size_t)row * 144;
    const float a0 = act[row * 3], a1 = act[row * 3 + 1], a2 = act[row * 3 + 2];
    const int wv = tid >> 6, lane = tid & 63;
    const int fr = lane & 15, kq = lane >> 4;

    bf16x8 bfrA[4], bfrB[4];
    int curH = 0, curO = 0;

    auto prefetchB = [&](int sn) {
#pragma unroll
        for (int n = 0; n < 4; n++)
            bfrB[n] = *(const bf16x8*)&w2t[(sn * 64 + n * 16 + fr) * 32 + kq * 8];
    };
    auto storeOut = [&](int sp, int bO) {
#pragma unroll
        for (int h = 0; h < 2; h++) {
            const int c = tid + h * 256;
            const int r = c >> 3, ch = c & 7;
            const bf16x8 v = *(const bf16x8*)&sO[bO][r * 72 + ch * 8];
            *(bf16x8*)&enc[((size_t)blockIdx.x * 64 + r) * 896 + sp * 64 + ch * 8] = v;
        }
    };
    auto l2c = [&](int s, int bH, int bO) {
        const bf16x8 afr = *(const bf16x8*)&sH[bH][(wv * 16 + fr) * 40 + kq * 8];
        f32x4 acc[4] = {};
#pragma unroll
        for (int n = 0; n < 4; n++)
            acc[n] = __builtin_amdgcn_mfma_f32_16x16x32_bf16(afr, bfrA[n], acc[n], 0, 0, 0);
        const float* b2 = sW + 3520 + s * 64;
#pragma unroll
        for (int n = 0; n < 4; n++) {
            const float bv = b2[n * 16 + fr];
#pragma unroll
            for (int rg = 0; rg < 4; rg++) {
                float v = acc[n][rg] + bv;
                v = fmaxf(v, 0.01f * v);
                sO[bO][(wv * 16 + kq * 4 + rg) * 72 + n * 16 + fr] = (__bf16)v;
            }
        }
    };

#define L1(DIN, W1OFF, SGI, DH, XLOAD)                               \
    {                                                                \
        float x[DIN];                                                \
        XLOAD;                                                       \
        const float* w1 = sW + (W1OFF);                              \
        const float* b1 = sW + 3072 + (SGI) * 32;                    \
        bf16x8 t_;                                                   \
        _Pragma("unroll") for (int j = 0; j < 8; j++) {              \
            const int o = q * 8 + j;                                 \
            float a_ = b1[o];                                        \
            _Pragma("unroll") for (int i = 0; i < DIN; i++)          \
                a_ += x[i] * w1[i * 32 + o];                         \
            t_[j] = (__bf16)fmaxf(a_, 0.01f * a_);                   \
        }                                                            \
        *(bf16x8*)&sH[DH][rloc * 40 + q * 8] = t_;                   \
    }

#define PROPX(K) { x[0] = orow[2 * (K)]; x[1] = orow[2 * (K) + 1]; x[2] = a0; x[3] = a1; x[4] = a2; }
#define TEAMX(K) { _Pragma("unroll") for (int i = 0; i < 12; i++) x[i] = orow[18 + 12 * (K) + i]; }
#define RIVX(K)  { _Pragma("unroll") for (int i = 0; i < 9; i++) x[i] = orow[117 + 9 * (K) + i]; }

#define STEP(S, NEXTL1)                                              \
    __syncthreads();                                                 \
    if ((S) < 13) prefetchB((S) + 1);                                \
    if ((S) > 0) storeOut((S) - 1, curO ^ 1);                        \
    l2c((S), curH, curO);                                            \
    _Pragma("unroll") for (int n = 0; n < 4; n++) bfrA[n] = bfrB[n]; \
    NEXTL1                                                           \
    curH ^= 1; curO ^= 1;

    prefetchB(0);
    __syncthreads();
#pragma unroll
    for (int n = 0; n < 4; n++) bfrA[n] = bfrB[n];
    L1(5, 0, 0, 0, PROPX(0))

    STEP(0,  L1(5, 160, 1, curH ^ 1, PROPX(1)))
    STEP(1,  L1(5, 320, 2, curH ^ 1, PROPX(2)))
    STEP(2,  L1(5, 480, 3, curH ^ 1, PROPX(3)))
    STEP(3,  L1(5, 640, 4, curH ^ 1, PROPX(4)))
    STEP(4,  L1(5, 800, 5, curH ^ 1, PROPX(5)))
    STEP(5,  L1(5, 960, 6, curH ^ 1, PROPX(6)))
    STEP(6,  L1(5, 1120, 7, curH ^ 1, PROPX(7)))
    STEP(7,  L1(5, 1280, 8, curH ^ 1, PROPX(8)))
    STEP(8,  L1(12, 1440, 9, curH ^ 1, TEAMX(0)))
    STEP(9,  L1(12, 1824, 10, curH ^ 1, TEAMX(1)))
    STEP(10, L1(9, 2208, 11, curH ^ 1, RIVX(0)))
    STEP(11, L1(9, 2496, 12, curH ^ 1, RIVX(1)))
    STEP(12, L1(9, 2784, 13, curH ^ 1, RIVX(2)))
    STEP(13, )

    __syncthreads();
    storeOut(13, curO ^ 1);
#undef STEP
#undef L1
#undef PROPX
#undef TEAMX
#undef RIVX
}

// ---------------- GEMM1: 256x256, 32x32x16 MFMA, R8 waits, STRENGTHENED swizzle ----------------
// R19's slot = g ^ (row&7) conflicted 8.26M times (only 2 k-groups in lanes vs 16x16's 4).
// Fix: swz(row) = (row&7) ^ (((row>>3)&3)<<1); phys slot = g ^ swz(row). Bijective per
// row; lanes grouped by stride-1 OR stride-8 rows now land on 8 distinct slots.
// Both-sides: staging source offset and read slot use the same swz (rule #21).
__global__ __launch_bounds__(512, 2) void gemm32_relu(const __bf16* __restrict__ Ag,
                                                      const __bf16* __restrict__ Btg,
                                                      const float* __restrict__ bias,
                                                      __bf16* __restrict__ Cg,
                                                      int N, int K, int lgn) {
    __shared__ __align__(16) __bf16 ldsF[65536];   // A: 4x8192 | B: 4x8192 (2buf x 2half)
    const int tid = threadIdx.x;
    const int wid = tid >> 6, lane = tid & 63;
    const int wm = wid >> 2, wn = wid & 3;
    const int l31 = lane & 31, l5 = lane >> 5;

    const int chunk = gridDim.x >> 3;
    const int wg = (blockIdx.x & 7) * chunk + (blockIdx.x >> 3);
    const int bn = wg & ((1 << lgn) - 1), bm = wg >> lgn;

    const int c0 = tid, c1 = tid + 512;
    const int r0 = c0 >> 3, s0 = (c0 & 7) ^ (r0 & 7) ^ (((r0 >> 3) & 3) << 1);
    const int r1 = c1 >> 3, s1 = (c1 & 7) ^ (r1 & 7) ^ (((r1 >> 3) & 3) << 1);
    const size_t aH = (size_t)128 * K;
    const size_t bH = (size_t)128 * K;
    const __bf16* aB0 = Ag + (size_t)(bm * 256 + r0) * K + s0 * 8;
    const __bf16* aB1 = Ag + (size_t)(bm * 256 + r1) * K + s1 * 8;
    const __bf16* bB0 = Btg + (size_t)(bn * 256 + r0) * K + s0 * 8;
    const __bf16* bB1 = Btg + (size_t)(bn * 256 + r1) * K + s1 * 8;

    // read-side swizzle for fragment rows (wm/m2/wn contribute 0 mod 8 and 0 mod 4<<3)
    const int rsw = (l31 & 7) ^ (((l31 >> 3) & 3) << 1);

    f32x16 acc[2][2][2] = {};          // [q = A-half][r2 = B-half][m2]
    bf16x8 a0[2][4], a1[2][4];         // [m2][ks]
    bf16x8 b0[4], b1[4];               // [ks]

#define LDSA(BUF, H) (ldsF + ((BUF) * 2 + (H)) * 8192)
#define LDSB(BUF, H) (ldsF + 32768 + ((BUF) * 2 + (H)) * 8192)

#define STAGE_A(BUF, H, KO)                                   \
    do {                                                      \
        __bf16* d_ = LDSA(BUF, H);                            \
        gld16(aB0 + (H)*aH + (KO), d_ + c0 * 8);              \
        gld16(aB1 + (H)*aH + (KO), d_ + c1 * 8);              \
    } while (0)
#define STAGE_B(BUF, H, KO)                                   \
    do {                                                      \
        __bf16* d_ = LDSB(BUF, H);                            \
        gld16(bB0 + (H)*bH + (KO), d_ + c0 * 8);              \
        gld16(bB1 + (H)*bH + (KO), d_ + c1 * 8);              \
    } while (0)

#define LOAD_A32(BUF, H, DST)                                                      \
    _Pragma("unroll") for (int m2 = 0; m2 < 2; m2++)                               \
        _Pragma("unroll") for (int ks = 0; ks < 4; ks++)                           \
            DST[m2][ks] = *(const bf16x8*)&LDSA(BUF, H)[(wm * 64 + m2 * 32 + l31) * 64 + \
                          (((ks * 2 + l5) ^ rsw) * 8)];
#define LOAD_B32(BUF, H, DST)                                                      \
    _Pragma("unroll") for (int ks = 0; ks < 4; ks++)                               \
        DST[ks] = *(const bf16x8*)&LDSB(BUF, H)[(wn * 32 + l31) * 64 +             \
                  (((ks * 2 + l5) ^ rsw) * 8)];

#define MM32(Q, R, AR, BR)                                    \
    __builtin_amdgcn_s_setprio(1);                            \
    _Pragma("unroll") for (int ks = 0; ks < 4; ks++)          \
        _Pragma("unroll") for (int m2 = 0; m2 < 2; m2++)      \
            acc[Q][R][m2] = __builtin_amdgcn_mfma_f32_32x32x16_bf16( \
                AR[m2][ks], BR[ks], acc[Q][R][m2], 0, 0, 0);  \
    __builtin_amdgcn_s_setprio(0);

#define SB0 __builtin_amdgcn_sched_barrier(0)
#define BAR __builtin_amdgcn_s_barrier()
#define LGKM(NSTR) asm volatile("s_waitcnt lgkmcnt(" NSTR ")" ::: "memory")
#define VMW(NSTR) asm volatile("s_waitcnt vmcnt(" NSTR ")" ::: "memory")

    const int NT = K >> 6;

    // ---- R8 wait structure, verbatim ----
    STAGE_A(0, 0, 0);
    STAGE_B(0, 0, 0);
    STAGE_B(0, 1, 0);
    STAGE_A(0, 1, 0);
    VMW("2");
    BAR;
    LOAD_A32(0, 0, a0)
    LOAD_B32(0, 0, b0)
    SB0;

    for (int t = 0; t < NT - 1; ++t) {
        const int buf = t & 1, nb = buf ^ 1;
        const int kO = (t + 1) << 6;

        // W1: stage A0',B0'; vmcnt covers A1(t)
        STAGE_A(nb, 0, kO);
        STAGE_B(nb, 0, kO);
        VMW("4");
        LOAD_B32(buf, 1, b1)      // B1(t): covered by W4(t-1) VMW(2)+BAR
        SB0;
        BAR;
        LGKM("4");                // a0,b0 done; b1 in flight
        SB0;
        MM32(0, 0, a0, b0)

        // W2: stage B1',A1'
        STAGE_B(nb, 1, kO);
        STAGE_A(nb, 1, kO);
        LOAD_A32(buf, 1, a1)      // A1(t): covered by W1 VMW(4)+BAR
        SB0;
        BAR;
        LGKM("8");                // b1 done; a1 in flight
        SB0;
        MM32(0, 1, a0, b1)

        // W3
        BAR;
        LGKM("0");
        SB0;
        MM32(1, 0, a1, b0)

        // W4: cover A0',B0',B1' (leaves only A1' in flight)
        VMW("2");
        BAR;
        LOAD_A32(nb, 0, a0)
        LOAD_B32(nb, 0, b0)
        SB0;
        MM32(1, 1, a1, b1)
    }
    // peeled last tile
    {
        const int buf = (NT - 1) & 1;
        VMW("0");
        LOAD_B32(buf, 1, b1)
        SB0;
        BAR;
        LGKM("4");
        SB0;
        MM32(0, 0, a0, b0)

        LOAD_A32(buf, 1, a1)
        SB0;
        BAR;
        LGKM("8");
        SB0;
        MM32(0, 1, a0, b1)

        BAR;
        LGKM("0");
        SB0;
        MM32(1, 0, a1, b0)

        MM32(1, 1, a1, b1)
    }

    // epilogue: C/D 32x32 layout — col=lane&31, row=(reg&3)+8*(reg>>2)+4*(lane>>5)
#pragma unroll
    for (int q = 0; q < 2; q++)
#pragma unroll
        for (int r2 = 0; r2 < 2; r2++) {
            const int colG = bn * 256 + r2 * 128 + wn * 32 + l31;
            const float bv = bias[colG];
#pragma unroll
            for (int m2 = 0; m2 < 2; m2++) {
                const int rowB = bm * 256 + q * 128 + wm * 64 + m2 * 32 + 4 * l5;
#pragma unroll
                for (int reg = 0; reg < 16; reg++) {
                    const int rowG = rowB + (reg & 3) + 8 * (reg >> 2);
                    float v = acc[q][r2][m2][reg] + bv;
                    v = fmaxf(v, 0.0f);
                    Cg[(size_t)rowG * N + colG] = (__bf16)v;
                }
            }
        }
#undef LDSA
#undef LDSB
#undef STAGE_A
#undef STAGE_B
#undef LOAD_A32
#undef LOAD_B32
#undef MM32
#undef SB0
#undef BAR
#undef LGKM
#undef VMW
}

// ---------------- GEMM2: 256x128 single-barrier tile + fused 512->3 head (validated) ----------------
template <int NB, bool HEAD>
__global__ __launch_bounds__(512, 2) void gemm256_relu(const __bf16* __restrict__ Ag,
                                                       const __bf16* __restrict__ Btg,
                                                       const float* __restrict__ bias,
                                                       __bf16* __restrict__ Cg,
                                                       const float* __restrict__ Wq3,
                                                       float* __restrict__ pout,
                                                       int N, int K, int lgn) {
    __shared__ __align__(16) __bf16 ldsF[32768 + 2 * 2 * NB * 4096];
    const int tid = threadIdx.x;
    const int wid = tid >> 6, lane = tid & 63;
    const int wm = wid >> 2, wn = wid & 3;
    const int fr = lane & 15, kq = lane >> 4;

    const int chunk = gridDim.x >> 3;
    const int wg = (blockIdx.x & 7) * chunk + (blockIdx.x >> 3);
    const int bn = wg & ((1 << lgn) - 1), bm = wg >> lgn;

    const int c0 = tid, c1 = tid + 512;
    const int r0 = c0 >> 3, s0 = (c0 & 7) ^ (r0 & 7);
    const int r1 = c1 >> 3, s1 = (c1 & 7) ^ (r1 & 7);
    const size_t aH = (size_t)128 * K;
    const size_t bH = (size_t)(NB * 64) * K;
    const __bf16* aB0 = Ag + (size_t)(bm * 256 + r0) * K + s0 * 8;
    const __bf16* aB1 = Ag + (size_t)(bm * 256 + r1) * K + s1 * 8;
    const __bf16* bB0 = Btg + (size_t)(bn * (NB * 128) + r0) * K + s0 * 8;
    const __bf16* bB1 = Btg + (size_t)(bn * (NB * 128) + r1) * K + s1 * 8;

    f32x4 acc[2][2][4][NB] = {};
    bf16x8 a0[4][2], a1[4][2], b0[NB][2], b1[NB][2];

#define LDSA(BUF, H) (ldsF + ((BUF) * 2 + (H)) * 8192)
#define LDSB(BUF, H) (ldsF + 32768 + ((BUF) * 2 + (H)) * (NB * 4096))

#define STAGE_A(BUF, H, KO)                                   \
    do {                                                      \
        __bf16* d_ = LDSA(BUF, H);                            \
        gld16(aB0 + (H)*aH + (KO), d_ + c0 * 8);              \
        gld16(aB1 + (H)*aH + (KO), d_ + c1 * 8);              \
    } while (0)
#define STAGE_B(BUF, H, KO)                                   \
    do {                                                      \
        __bf16* d_ = LDSB(BUF, H);                            \
        gld16(bB0 + (H)*bH + (KO), d_ + c0 * 8);              \
        if constexpr (NB == 2) gld16(bB1 + (H)*bH + (KO), d_ + c1 * 8); \
    } while (0)

#define LDFA(BUF, H, ROW, KS) \
    (*(const bf16x8*)&LDSA(BUF, H)[(ROW) * 64 + ((((KS)*4 + kq) ^ ((ROW)&7)) * 8)])
#define LDFB(BUF, H, ROW, KS) \
    (*(const bf16x8*)&LDSB(BUF, H)[(ROW) * 64 + ((((KS)*4 + kq) ^ ((ROW)&7)) * 8)])

#define LOAD_A(BUF, H, DST)                                   \
    _Pragma("unroll") for (int m = 0; m < 4; m++)             \
        _Pragma("unroll") for (int ks = 0; ks < 2; ks++)      \
            DST[m][ks] = LDFA(BUF, H, wm * 64 + m * 16 + fr, ks);
#define LOAD_B(BUF, H, DST)                                   \
    _Pragma("unroll") for (int n = 0; n < NB; n++)            \
        _Pragma("unroll") for (int ks = 0; ks < 2; ks++)      \
            DST[n][ks] = LDFB(BUF, H, wn * (NB * 16) + n * 16 + fr, ks);

#define MM(Q, R, AR, BR)                                      \
    __builtin_amdgcn_s_setprio(1);                            \
    _Pragma("unroll") for (int ks = 0; ks < 2; ks++)          \
        _Pragma("unroll") for (int m = 0; m < 4; m++)         \
            _Pragma("unroll") for (int n = 0; n < NB; n++)    \
                acc[Q][R][m][n] = __builtin_amdgcn_mfma_f32_16x16x32_bf16( \
                    AR[m][ks], BR[n][ks], acc[Q][R][m][n], 0, 0, 0); \
    __builtin_amdgcn_s_setprio(0);

#define SB0 __builtin_amdgcn_sched_barrier(0)
#define BAR __builtin_amdgcn_s_barrier()
#define LGKM(NSTR) asm volatile("s_waitcnt lgkmcnt(" NSTR ")" ::: "memory")
#define LGKM2(N2, N1)                                         \
    if constexpr (NB == 2) LGKM(#N2); else LGKM(#N1);
#define VMW(NSTR) asm volatile("s_waitcnt vmcnt(" NSTR ")" ::: "memory")

    const int NT = K >> 6;

    STAGE_A(0, 0, 0);
    STAGE_B(0, 0, 0);
    STAGE_B(0, 1, 0);
    STAGE_A(0, 1, 0);

    for (int t = 0; t < NT; ++t) {
        const int buf = t & 1, nb = buf ^ 1;
        const int kO = (t + 1) << 6;

        VMW("0");
        BAR;
        LOAD_A(buf, 0, a0)
        LOAD_B(buf, 0, b0)
        SB0;
        if (t + 1 < NT) {
            STAGE_A(nb, 0, kO);
            STAGE_B(nb, 0, kO);
            STAGE_B(nb, 1, kO);
            STAGE_A(nb, 1, kO);
        }
        SB0;
        LOAD_B(buf, 1, b1)
        LOAD_A(buf, 1, a1)
        SB0;
        LGKM2(12, 10);
        SB0;
        MM(0, 0, a0, b0)
        LGKM("8");
        SB0;
        MM(0, 1, a0, b1)
        LGKM("0");
        SB0;
        MM(1, 0, a1, b0)
        MM(1, 1, a1, b1)
    }

    const int cc = lane & 15, rr = (lane >> 4) << 2;
    if constexpr (!HEAD) {
#pragma unroll
        for (int q = 0; q < 2; q++)
#pragma unroll
            for (int r2 = 0; r2 < 2; r2++)
#pragma unroll
                for (int m = 0; m < 4; m++)
#pragma unroll
                    for (int n = 0; n < NB; n++) {
                        const int colG = bn * (NB * 128) + r2 * (NB * 64) + wn * (NB * 16) + n * 16 + cc;
                        const int rowG = bm * 256 + q * 128 + wm * 64 + m * 16 + rr;
                        const float bv = bias[colG];
#pragma unroll
                        for (int reg = 0; reg < 4; reg++) {
                            float v = acc[q][r2][m][n][reg] + bv;
                            v = fmaxf(v, 0.0f);
                            Cg[(size_t)(rowG + reg) * N + colG] = (__bf16)v;
                        }
                    }
    } else {
        // fused head epilogue (NB==1): hS[256 rows][16 slots of 8], phys slot = logical ^ (row&7)
        __syncthreads();
        __bf16* hS = ldsF;
#pragma unroll
        for (int q = 0; q < 2; q++)
#pragma unroll
            for (int r2 = 0; r2 < 2; r2++)
#pragma unroll
                for (int m = 0; m < 4; m++) {
                    const int colL = r2 * 64 + wn * 16 + cc;
                    const int rowL0 = q * 128 + wm * 64 + m * 16 + rr;
                    const float bv = bias[bn * 128 + colL];
                    const int slot = colL >> 3, pos = colL & 7;
#pragma unroll
                    for (int reg = 0; reg < 4; reg++) {
                        const int rowL = rowL0 + reg;
                        float v = acc[q][r2][m][0][reg] + bv;
                        v = fmaxf(v, 0.0f);
                        hS[rowL * 128 + (slot ^ (rowL & 7)) * 8 + pos] = (__bf16)v;
                    }
                }
        __syncthreads();
        const int rowL = tid >> 1, half = tid & 1;
        float s0v = 0.f, s1v = 0.f, s2v = 0.f;
#pragma unroll
        for (int c8 = 0; c8 < 8; c8++) {
            const int lslot = half * 8 + c8;
            const int pslot = half * 8 + (c8 ^ (rowL & 7));
            const bf16x8 hv = *(const bf16x8*)&hS[rowL * 128 + pslot * 8];
#pragma unroll
            for (int j = 0; j < 8; j++) {
                const float hf = (float)hv[j];
                const int col = bn * 128 + lslot * 8 + j;
                s0v += hf * Wq3[col * 3 + 0];
                s1v += hf * Wq3[col * 3 + 1];
                s2v += hf * Wq3[col * 3 + 2];
            }
        }
        s0v += __shfl_xor(s0v, 1);
        s1v += __shfl_xor(s1v, 1);
        s2v += __shfl_xor(s2v, 1);
        if (!half) {
            float* p = pout + ((size_t)(bm * 256 + rowL) * 4 + bn) * 3;
            p[0] = s0v; p[1] = s1v; p[2] = s2v;
        }
    }
#undef LDSA
#undef LDSB
#undef STAGE_A
#undef STAGE_B
#undef LDFA
#undef LDFB
#undef LOAD_A
#undef LOAD_B
#undef MM
#undef SB0
#undef BAR
#undef LGKM
#undef LGKM2
#undef VMW
}

// ---------------- reduce: out[row][j] = sum_bn pout[row][bn][j] + bq3[j] ----------------
__global__ __launch_bounds__(256) void reduce_head(const float* __restrict__ pout,
                                                   const float* __restrict__ bq3,
                                                   float* __restrict__ out) {
    const int row = blockIdx.x * 256 + threadIdx.x;
    const float* p = pout + (size_t)row * 12;
#pragma unroll
    for (int j = 0; j < 3; j++)
        out[(size_t)row * 3 + j] = p[j] + p[3 + j] + p[6 + j] + p[9 + j] + bq3[j];
}

extern "C" void kernel_launch(void* const* d_in, const int* in_sizes, int n_in,
                              void* d_out, int out_size, void* d_ws, size_t ws_size,
                              hipStream_t stream) {
    const float* obs = (const float*)d_in[0];
    const float* act = (const float*)d_in[1];
    const float* Wp1 = (const float*)d_in[2];  const float* bp1 = (const float*)d_in[3];
    const float* Wp2 = (const float*)d_in[4];  const float* bp2 = (const float*)d_in[5];
    const float* Wt1 = (const float*)d_in[6];  const float* bt1 = (const float*)d_in[7];
    const float* Wt2 = (const float*)d_in[8];  const float* bt2 = (const float*)d_in[9];
    const float* Wr1 = (const float*)d_in[10]; const float* br1 = (const float*)d_in[11];
    const float* Wr2 = (const float*)d_in[12]; const float* br2 = (const float*)d_in[13];
    const float* Wq1 = (const float*)d_in[14]; const float* bq1 = (const float*)d_in[15];
    const float* Wq2 = (const float*)d_in[16]; const float* bq2 = (const float*)d_in[17];
    const float* Wq3 = (const float*)d_in[18]; const float* bq3 = (const float*)d_in[19];
    float* out = (float*)d_out;

    char* ws = (char*)d_ws;
    __bf16* enc  = (__bf16*)(ws);                            // 88,080,384
    __bf16* h1   = (__bf16*)(ws + 88080384);                 // 33,554,432
    float*  pout = (float*)(ws + 88080384 + 33554432);       // 786,432
    __bf16* w1t  = (__bf16*)(ws + 138412032);                // 5,505,024
    __bf16* w2t  = (__bf16*)(ws + 143917056);                // 1,048,576
    float*  w1p  = (float*)(ws + 144965632);                 // 17,664
    __bf16* w2e  = (__bf16*)(ws + 144983296);                // 57,344

    // fused weight prep (2 transposes + encoder pack in one launch)
    prep_all<<<814, 256, 0, stream>>>(Wq1, Wq2, Wp1, bp1, Wp2, bp2, Wt1, bt1, Wt2, bt2,
                                      Wr1, br1, Wr2, br2, w1t, w2t, w1p, w2e);

    // fused encoders: 49152 rows, 64 rows/block, 768 blocks (3/CU)
    enc_fused<<<768, 256, 0, stream>>>(obs, act, w1p, w2e, enc);

    // q head: GEMM1 (32x32 MFMA, fixed swizzle), GEMM2 (single-barrier + fused head), reduce
    gemm32_relu<<<dim3(256), 512, 0, stream>>>(enc, w1t, bq1, h1, 1024, 2688, 2);
    gemm256_relu<1, true><<<dim3(256), 512, 0, stream>>>(h1, w2t, bq2, nullptr, Wq3, pout, 512, 1024, 2);
    reduce_head<<<64, 256, 0, stream>>>(pout, bq3, out);
}

// Round 22
// 135.617 us; speedup vs baseline: 1.0935x; 1.0935x over previous
//
#include <hip/hip_runtime.h>
#include <hip/hip_bf16.h>
#include <cstdint>

typedef __bf16 bf16x8 __attribute__((ext_vector_type(8)));
typedef float f32x4 __attribute__((ext_vector_type(4)));

// ---------------- async global->LDS (16B per lane) ----------------
__device__ __forceinline__ void gld16(const __bf16* g, __bf16* lds) {
    __builtin_amdgcn_global_load_lds(
        (__attribute__((address_space(1))) void*)(uintptr_t)g,
        (__attribute__((address_space(3))) void*)(uint32_t)(uintptr_t)lds,
        16, 0, 0);
}

// ---------------- fused weight prep: T(Wq1), T(Wq2), encoder pack — one launch ----------------
__global__ __launch_bounds__(256) void prep_all(const float* __restrict__ Wq1, const float* __restrict__ Wq2,
                                                const float* __restrict__ Wp1, const float* __restrict__ bp1,
                                                const float* __restrict__ Wp2, const float* __restrict__ bp2,
                                                const float* __restrict__ Wt1, const float* __restrict__ bt1,
                                                const float* __restrict__ Wt2, const float* __restrict__ bt2,
                                                const float* __restrict__ Wr1, const float* __restrict__ br1,
                                                const float* __restrict__ Wr2, const float* __restrict__ br2,
                                                __bf16* __restrict__ w1t, __bf16* __restrict__ w2t,
                                                float* __restrict__ w1p, __bf16* __restrict__ w2e) {
    __shared__ float t[64][65];
    const int idx = blockIdx.x, tid = threadIdx.x;
    if (idx < 800) {
        const float* in; __bf16* out; int R, C, bx, by;
        if (idx < 672) { in = Wq1; out = w1t; R = 2688; C = 1024; bx = idx % 42; by = idx / 42; }
        else { const int i2 = idx - 672; in = Wq2; out = w2t; R = 1024; C = 512; bx = i2 % 16; by = i2 / 16; }
        const int r0 = bx * 64, c0 = by * 64;
#pragma unroll
        for (int i = 0; i < 16; i++) {
            int id2 = i * 256 + tid;
            int rr = id2 >> 6, cc = id2 & 63;
            t[rr][cc] = in[(size_t)(r0 + rr) * C + (c0 + cc)];
        }
        __syncthreads();
#pragma unroll
        for (int i = 0; i < 16; i++) {
            int id2 = i * 256 + tid;
            int rr = id2 >> 6, cc = id2 & 63;
            out[(size_t)(c0 + rr) * R + (r0 + cc)] = (__bf16)t[cc][rr];
        }
    } else {
        const int s = idx - 800;
        int ks, din, w1off;
        const float *W1, *B1, *W2, *B2;
        if (s < 9)      { ks = s;      din = 5;  w1off = s * 160;
                          W1 = Wp1; B1 = bp1; W2 = Wp2; B2 = bp2; }
        else if (s < 11){ ks = s - 9;  din = 12; w1off = 1440 + ks * 384;
                          W1 = Wt1; B1 = bt1; W2 = Wt2; B2 = bt2; }
        else            { ks = s - 11; din = 9;  w1off = 2208 + ks * 288;
                          W1 = Wr1; B1 = br1; W2 = Wr2; B2 = br2; }
        W1 += ks * din * 32; B1 += ks * 32; W2 += ks * 2048; B2 += ks * 64;
        for (int i = tid; i < din * 32; i += 256) w1p[w1off + i] = W1[i];
        if (tid < 32) w1p[3072 + s * 32 + tid] = B1[tid];
        if (tid < 64) w1p[3520 + s * 64 + tid] = B2[tid];
        for (int i = tid; i < 2048; i += 256) {
            const int o = i >> 5, k = i & 31;
            w2e[s * 2048 + i] = (__bf16)W2[k * 64 + o];
        }
    }
}

// ---------------- fused encoder v3: w2t prefetch pipeline + b128 stores via LDS ----------------
__global__ __launch_bounds__(256) void enc_fused(const float* __restrict__ obs,
                                                 const float* __restrict__ act,
                                                 const float* __restrict__ w1p,
                                                 const __bf16* __restrict__ w2t,
                                                 __bf16* __restrict__ enc) {
    __shared__ float sW[4416];
    __shared__ __bf16 sH[2][64 * 40];
    __shared__ __align__(16) __bf16 sO[2][64 * 72];
    const int tid = threadIdx.x;
    for (int i = tid; i < 4416; i += 256) sW[i] = w1p[i];
    const int rloc = tid >> 2, q = tid & 3;
    const int row = blockIdx.x * 64 + rloc;
    const float* orow = obs + (size_t)row * 144;
    const float a0 = act[row * 3], a1 = act[row * 3 + 1], a2 = act[row * 3 + 2];
    const int wv = tid >> 6, lane = tid & 63;
    const int fr = lane & 15, kq = lane >> 4;

    bf16x8 bfrA[4], bfrB[4];
    int curH = 0, curO = 0;

    auto prefetchB = [&](int sn) {
#pragma unroll
        for (int n = 0; n < 4; n++)
            bfrB[n] = *(const bf16x8*)&w2t[(sn * 64 + n * 16 + fr) * 32 + kq * 8];
    };
    auto storeOut = [&](int sp, int bO) {
#pragma unroll
        for (int h = 0; h < 2; h++) {
            const int c = tid + h * 256;
            const int r = c >> 3, ch = c & 7;
            const bf16x8 v = *(const bf16x8*)&sO[bO][r * 72 + ch * 8];
            *(bf16x8*)&enc[((size_t)blockIdx.x * 64 + r) * 896 + sp * 64 + ch * 8] = v;
        }
    };
    auto l2c = [&](int s, int bH, int bO) {
        const bf16x8 afr = *(const bf16x8*)&sH[bH][(wv * 16 + fr) * 40 + kq * 8];
        f32x4 acc[4] = {};
#pragma unroll
        for (int n = 0; n < 4; n++)
            acc[n] = __builtin_amdgcn_mfma_f32_16x16x32_bf16(afr, bfrA[n], acc[n], 0, 0, 0);
        const float* b2 = sW + 3520 + s * 64;
#pragma unroll
        for (int n = 0; n < 4; n++) {
            const float bv = b2[n * 16 + fr];
#pragma unroll
            for (int rg = 0; rg < 4; rg++) {
                float v = acc[n][rg] + bv;
                v = fmaxf(v, 0.01f * v);
                sO[bO][(wv * 16 + kq * 4 + rg) * 72 + n * 16 + fr] = (__bf16)v;
            }
        }
    };

#define L1(DIN, W1OFF, SGI, DH, XLOAD)                               \
    {                                                                \
        float x[DIN];                                                \
        XLOAD;                                                       \
        const float* w1 = sW + (W1OFF);                              \
        const float* b1 = sW + 3072 + (SGI) * 32;                    \
        bf16x8 t_;                                                   \
        _Pragma("unroll") for (int j = 0; j < 8; j++) {              \
            const int o = q * 8 + j;                                 \
            float a_ = b1[o];                                        \
            _Pragma("unroll") for (int i = 0; i < DIN; i++)          \
                a_ += x[i] * w1[i * 32 + o];                         \
            t_[j] = (__bf16)fmaxf(a_, 0.01f * a_);                   \
        }                                                            \
        *(bf16x8*)&sH[DH][rloc * 40 + q * 8] = t_;                   \
    }

#define PROPX(K) { x[0] = orow[2 * (K)]; x[1] = orow[2 * (K) + 1]; x[2] = a0; x[3] = a1; x[4] = a2; }
#define TEAMX(K) { _Pragma("unroll") for (int i = 0; i < 12; i++) x[i] = orow[18 + 12 * (K) + i]; }
#define RIVX(K)  { _Pragma("unroll") for (int i = 0; i < 9; i++) x[i] = orow[117 + 9 * (K) + i]; }

#define STEP(S, NEXTL1)                                              \
    __syncthreads();                                                 \
    if ((S) < 13) prefetchB((S) + 1);                                \
    if ((S) > 0) storeOut((S) - 1, curO ^ 1);                        \
    l2c((S), curH, curO);                                            \
    _Pragma("unroll") for (int n = 0; n < 4; n++) bfrA[n] = bfrB[n]; \
    NEXTL1                                                           \
    curH ^= 1; curO ^= 1;

    prefetchB(0);
    __syncthreads();
#pragma unroll
    for (int n = 0; n < 4; n++) bfrA[n] = bfrB[n];
    L1(5, 0, 0, 0, PROPX(0))

    STEP(0,  L1(5, 160, 1, curH ^ 1, PROPX(1)))
    STEP(1,  L1(5, 320, 2, curH ^ 1, PROPX(2)))
    STEP(2,  L1(5, 480, 3, curH ^ 1, PROPX(3)))
    STEP(3,  L1(5, 640, 4, curH ^ 1, PROPX(4)))
    STEP(4,  L1(5, 800, 5, curH ^ 1, PROPX(5)))
    STEP(5,  L1(5, 960, 6, curH ^ 1, PROPX(6)))
    STEP(6,  L1(5, 1120, 7, curH ^ 1, PROPX(7)))
    STEP(7,  L1(5, 1280, 8, curH ^ 1, PROPX(8)))
    STEP(8,  L1(12, 1440, 9, curH ^ 1, TEAMX(0)))
    STEP(9,  L1(12, 1824, 10, curH ^ 1, TEAMX(1)))
    STEP(10, L1(9, 2208, 11, curH ^ 1, RIVX(0)))
    STEP(11, L1(9, 2496, 12, curH ^ 1, RIVX(1)))
    STEP(12, L1(9, 2784, 13, curH ^ 1, RIVX(2)))
    STEP(13, )

    __syncthreads();
    storeOut(13, curO ^ 1);
#undef STEP
#undef L1
#undef PROPX
#undef TEAMX
#undef RIVX
}

// ---------------- 256xBN bf16 GEMM ----------------
// SCHED=0: R8 counted-vmcnt pipeline — 76.0 µs / 50.3% MfmaUtil, measured 5x.
//   CLOSED axes (all regressed): end-barriers -12% (R9), tile-burst -3% (R13),
//   balanced+extra-vmcnt -9% (R14), m201 paired-barrier combo -14% (R17),
//   32x32x16 shape -15% (R19/R21: structural LDS conflicts, swizzle-invariant).
// SCHED=1: single-barrier tile (best for GEMM2).
// HEAD: fused 512->3 head epilogue (partials to pout, no atomics).
template <int NB, bool HEAD, int SCHED>
__global__ __launch_bounds__(512, 2) void gemm256_relu(const __bf16* __restrict__ Ag,
                                                       const __bf16* __restrict__ Btg,
                                                       const float* __restrict__ bias,
                                                       __bf16* __restrict__ Cg,
                                                       const float* __restrict__ Wq3,
                                                       float* __restrict__ pout,
                                                       int N, int K, int lgn) {
    __shared__ __align__(16) __bf16 ldsF[32768 + 2 * 2 * NB * 4096];
    const int tid = threadIdx.x;
    const int wid = tid >> 6, lane = tid & 63;
    const int wm = wid >> 2, wn = wid & 3;
    const int fr = lane & 15, kq = lane >> 4;

    const int chunk = gridDim.x >> 3;
    const int wg = (blockIdx.x & 7) * chunk + (blockIdx.x >> 3);
    const int bn = wg & ((1 << lgn) - 1), bm = wg >> lgn;

    const int c0 = tid, c1 = tid + 512;
    const int r0 = c0 >> 3, s0 = (c0 & 7) ^ (r0 & 7);
    const int r1 = c1 >> 3, s1 = (c1 & 7) ^ (r1 & 7);
    const size_t aH = (size_t)128 * K;
    const size_t bH = (size_t)(NB * 64) * K;
    const __bf16* aB0 = Ag + (size_t)(bm * 256 + r0) * K + s0 * 8;
    const __bf16* aB1 = Ag + (size_t)(bm * 256 + r1) * K + s1 * 8;
    const __bf16* bB0 = Btg + (size_t)(bn * (NB * 128) + r0) * K + s0 * 8;
    const __bf16* bB1 = Btg + (size_t)(bn * (NB * 128) + r1) * K + s1 * 8;

    f32x4 acc[2][2][4][NB] = {};
    bf16x8 a0[4][2], a1[4][2], b0[NB][2], b1[NB][2];

#define LDSA(BUF, H) (ldsF + ((BUF) * 2 + (H)) * 8192)
#define LDSB(BUF, H) (ldsF + 32768 + ((BUF) * 2 + (H)) * (NB * 4096))

#define STAGE_A(BUF, H, KO)                                   \
    do {                                                      \
        __bf16* d_ = LDSA(BUF, H);                            \
        gld16(aB0 + (H)*aH + (KO), d_ + c0 * 8);              \
        gld16(aB1 + (H)*aH + (KO), d_ + c1 * 8);              \
    } while (0)
#define STAGE_B(BUF, H, KO)                                   \
    do {                                                      \
        __bf16* d_ = LDSB(BUF, H);                            \
        gld16(bB0 + (H)*bH + (KO), d_ + c0 * 8);              \
        if constexpr (NB == 2) gld16(bB1 + (H)*bH + (KO), d_ + c1 * 8); \
    } while (0)

#define LDFA(BUF, H, ROW, KS) \
    (*(const bf16x8*)&LDSA(BUF, H)[(ROW) * 64 + ((((KS)*4 + kq) ^ ((ROW)&7)) * 8)])
#define LDFB(BUF, H, ROW, KS) \
    (*(const bf16x8*)&LDSB(BUF, H)[(ROW) * 64 + ((((KS)*4 + kq) ^ ((ROW)&7)) * 8)])

#define LOAD_A(BUF, H, DST)                                   \
    _Pragma("unroll") for (int m = 0; m < 4; m++)             \
        _Pragma("unroll") for (int ks = 0; ks < 2; ks++)      \
            DST[m][ks] = LDFA(BUF, H, wm * 64 + m * 16 + fr, ks);
#define LOAD_B(BUF, H, DST)                                   \
    _Pragma("unroll") for (int n = 0; n < NB; n++)            \
        _Pragma("unroll") for (int ks = 0; ks < 2; ks++)      \
            DST[n][ks] = LDFB(BUF, H, wn * (NB * 16) + n * 16 + fr, ks);

#define MM(Q, R, AR, BR)                                      \
    __builtin_amdgcn_s_setprio(1);                            \
    _Pragma("unroll") for (int ks = 0; ks < 2; ks++)          \
        _Pragma("unroll") for (int m = 0; m < 4; m++)         \
            _Pragma("unroll") for (int n = 0; n < NB; n++)    \
                acc[Q][R][m][n] = __builtin_amdgcn_mfma_f32_16x16x32_bf16( \
                    AR[m][ks], BR[n][ks], acc[Q][R][m][n], 0, 0, 0); \
    __builtin_amdgcn_s_setprio(0);

#define SB0 __builtin_amdgcn_sched_barrier(0)
#define BAR __builtin_amdgcn_s_barrier()
#define LGKM(NSTR) asm volatile("s_waitcnt lgkmcnt(" NSTR ")" ::: "memory")
#define LGKM2(N2, N1)                                         \
    if constexpr (NB == 2) LGKM(#N2); else LGKM(#N1);
#define VMW(NSTR) asm volatile("s_waitcnt vmcnt(" NSTR ")" ::: "memory")
#define VMW2(N2, N1)                                          \
    if constexpr (NB == 2) VMW(#N2); else VMW(#N1);

    const int NT = K >> 6;

    if constexpr (SCHED == 0) {
        // ---- R8 counted-vmcnt pipeline (verbatim; do not perturb) ----
        STAGE_A(0, 0, 0);
        STAGE_B(0, 0, 0);
        STAGE_B(0, 1, 0);
        STAGE_A(0, 1, 0);
        VMW("2");
        BAR;
        LOAD_A(0, 0, a0)
        LOAD_B(0, 0, b0)
        SB0;

        for (int t = 0; t < NT - 1; ++t) {
            const int buf = t & 1, nb = buf ^ 1;
            const int kO = (t + 1) << 6;

            // W1: stage A0',B0'; vmcnt covers A1(t)
            STAGE_A(nb, 0, kO);
            STAGE_B(nb, 0, kO);
            VMW2(4, 3);
            LOAD_B(buf, 1, b1)        // B1(t): covered by W4(t-1) VMW("2") + BAR
            SB0;
            BAR;
            LGKM2(4, 2);
            SB0;
            MM(0, 0, a0, b0)

            // W2: stage B1',A1'
            STAGE_B(nb, 1, kO);
            STAGE_A(nb, 1, kO);
            LOAD_A(buf, 1, a1)        // A1(t): covered by W1 VMW2(4,3) + BAR
            SB0;
            BAR;
            LGKM("8");
            SB0;
            MM(0, 1, a0, b1)

            // W3
            BAR;
            LGKM("0");
            SB0;
            MM(1, 0, a1, b0)

            // W4: cover A0',B0',B1' (leaves only A1' in flight)
            VMW("2");
            BAR;
            LOAD_A(nb, 0, a0)
            LOAD_B(nb, 0, b0)
            SB0;
            MM(1, 1, a1, b1)
        }
        // peeled last tile
        {
            const int buf = (NT - 1) & 1;
            VMW("0");
            LOAD_B(buf, 1, b1)
            SB0;
            BAR;
            LGKM2(4, 2);
            SB0;
            MM(0, 0, a0, b0)

            LOAD_A(buf, 1, a1)
            SB0;
            BAR;
            LGKM("8");
            SB0;
            MM(0, 1, a0, b1)

            BAR;
            LGKM("0");
            SB0;
            MM(1, 0, a1, b0)

            MM(1, 1, a1, b1)
        }
    } else {
        // ---- single-barrier tile schedule (best for GEMM2) ----
        STAGE_A(0, 0, 0);
        STAGE_B(0, 0, 0);
        STAGE_B(0, 1, 0);
        STAGE_A(0, 1, 0);

        for (int t = 0; t < NT; ++t) {
            const int buf = t & 1, nb = buf ^ 1;
            const int kO = (t + 1) << 6;

            VMW("0");
            BAR;
            LOAD_A(buf, 0, a0)
            LOAD_B(buf, 0, b0)
            SB0;
            if (t + 1 < NT) {
                STAGE_A(nb, 0, kO);
                STAGE_B(nb, 0, kO);
                STAGE_B(nb, 1, kO);
                STAGE_A(nb, 1, kO);
            }
            SB0;
            LOAD_B(buf, 1, b1)
            LOAD_A(buf, 1, a1)
            SB0;
            LGKM2(12, 10);
            SB0;
            MM(0, 0, a0, b0)
            LGKM("8");
            SB0;
            MM(0, 1, a0, b1)
            LGKM("0");
            SB0;
            MM(1, 0, a1, b0)
            MM(1, 1, a1, b1)
        }
    }

    const int cc = lane & 15, rr = (lane >> 4) << 2;
    if constexpr (!HEAD) {
#pragma unroll
        for (int q = 0; q < 2; q++)
#pragma unroll
            for (int r2 = 0; r2 < 2; r2++)
#pragma unroll
                for (int m = 0; m < 4; m++)
#pragma unroll
                    for (int n = 0; n < NB; n++) {
                        const int colG = bn * (NB * 128) + r2 * (NB * 64) + wn * (NB * 16) + n * 16 + cc;
                        const int rowG = bm * 256 + q * 128 + wm * 64 + m * 16 + rr;
                        const float bv = bias[colG];
#pragma unroll
                        for (int reg = 0; reg < 4; reg++) {
                            float v = acc[q][r2][m][n][reg] + bv;
                            v = fmaxf(v, 0.0f);
                            Cg[(size_t)(rowG + reg) * N + colG] = (__bf16)v;
                        }
                    }
    } else {
        // fused head epilogue (NB==1): hS[256 rows][16 slots of 8], phys slot = logical ^ (row&7)
        __syncthreads();
        __bf16* hS = ldsF;
#pragma unroll
        for (int q = 0; q < 2; q++)
#pragma unroll
            for (int r2 = 0; r2 < 2; r2++)
#pragma unroll
                for (int m = 0; m < 4; m++) {
                    const int colL = r2 * 64 + wn * 16 + cc;
                    const int rowL0 = q * 128 + wm * 64 + m * 16 + rr;
                    const float bv = bias[bn * 128 + colL];
                    const int slot = colL >> 3, pos = colL & 7;
#pragma unroll
                    for (int reg = 0; reg < 4; reg++) {
                        const int rowL = rowL0 + reg;
                        float v = acc[q][r2][m][0][reg] + bv;
                        v = fmaxf(v, 0.0f);
                        hS[rowL * 128 + (slot ^ (rowL & 7)) * 8 + pos] = (__bf16)v;
                    }
                }
        __syncthreads();
        const int rowL = tid >> 1, half = tid & 1;
        float s0v = 0.f, s1v = 0.f, s2v = 0.f;
#pragma unroll
        for (int c8 = 0; c8 < 8; c8++) {
            const int lslot = half * 8 + c8;
            const int pslot = half * 8 + (c8 ^ (rowL & 7));
            const bf16x8 hv = *(const bf16x8*)&hS[rowL * 128 + pslot * 8];
#pragma unroll
            for (int j = 0; j < 8; j++) {
                const float hf = (float)hv[j];
                const int col = bn * 128 + lslot * 8 + j;
                s0v += hf * Wq3[col * 3 + 0];
                s1v += hf * Wq3[col * 3 + 1];
                s2v += hf * Wq3[col * 3 + 2];
            }
        }
        s0v += __shfl_xor(s0v, 1);
        s1v += __shfl_xor(s1v, 1);
        s2v += __shfl_xor(s2v, 1);
        if (!half) {
            float* p = pout + ((size_t)(bm * 256 + rowL) * 4 + bn) * 3;
            p[0] = s0v; p[1] = s1v; p[2] = s2v;
        }
    }
#undef LDSA
#undef LDSB
#undef STAGE_A
#undef STAGE_B
#undef LDFA
#undef LDFB
#undef LOAD_A
#undef LOAD_B
#undef MM
#undef SB0
#undef BAR
#undef LGKM
#undef LGKM2
#undef VMW
#undef VMW2
}

// ---------------- reduce: out[row][j] = sum_bn pout[row][bn][j] + bq3[j] ----------------
__global__ __launch_bounds__(256) void reduce_head(const float* __restrict__ pout,
                                                   const float* __restrict__ bq3,
                                                   float* __restrict__ out) {
    const int row = blockIdx.x * 256 + threadIdx.x;
    const float* p = pout + (size_t)row * 12;
#pragma unroll
    for (int j = 0; j < 3; j++)
        out[(size_t)row * 3 + j] = p[j] + p[3 + j] + p[6 + j] + p[9 + j] + bq3[j];
}

extern "C" void kernel_launch(void* const* d_in, const int* in_sizes, int n_in,
                              void* d_out, int out_size, void* d_ws, size_t ws_size,
                              hipStream_t stream) {
    const float* obs = (const float*)d_in[0];
    const float* act = (const float*)d_in[1];
    const float* Wp1 = (const float*)d_in[2];  const float* bp1 = (const float*)d_in[3];
    const float* Wp2 = (const float*)d_in[4];  const float* bp2 = (const float*)d_in[5];
    const float* Wt1 = (const float*)d_in[6];  const float* bt1 = (const float*)d_in[7];
    const float* Wt2 = (const float*)d_in[8];  const float* bt2 = (const float*)d_in[9];
    const float* Wr1 = (const float*)d_in[10]; const float* br1 = (const float*)d_in[11];
    const float* Wr2 = (const float*)d_in[12]; const float* br2 = (const float*)d_in[13];
    const float* Wq1 = (const float*)d_in[14]; const float* bq1 = (const float*)d_in[15];
    const float* Wq2 = (const float*)d_in[16]; const float* bq2 = (const float*)d_in[17];
    const float* Wq3 = (const float*)d_in[18]; const float* bq3 = (const float*)d_in[19];
    float* out = (float*)d_out;

    char* ws = (char*)d_ws;
    __bf16* enc  = (__bf16*)(ws);                            // 88,080,384
    __bf16* h1   = (__bf16*)(ws + 88080384);                 // 33,554,432
    float*  pout = (float*)(ws + 88080384 + 33554432);       // 786,432
    __bf16* w1t  = (__bf16*)(ws + 138412032);                // 5,505,024
    __bf16* w2t  = (__bf16*)(ws + 143917056);                // 1,048,576
    float*  w1p  = (float*)(ws + 144965632);                 // 17,664
    __bf16* w2e  = (__bf16*)(ws + 144983296);                // 57,344

    // fused weight prep (2 transposes + encoder pack in one launch)
    prep_all<<<814, 256, 0, stream>>>(Wq1, Wq2, Wp1, bp1, Wp2, bp2, Wt1, bt1, Wt2, bt2,
                                      Wr1, br1, Wr2, br2, w1t, w2t, w1p, w2e);

    // fused encoders: 49152 rows, 64 rows/block, 768 blocks (3/CU)
    enc_fused<<<768, 256, 0, stream>>>(obs, act, w1p, w2e, enc);

    // q head: GEMM1 (R8 schedule), GEMM2 (single-barrier + fused head), reduce
    gemm256_relu<2, false, 0><<<dim3(256), 512, 0, stream>>>(enc, w1t, bq1, h1, nullptr, nullptr, 1024, 2688, 2);
    gemm256_relu<1, true, 1><<<dim3(256), 512, 0, stream>>>(h1, w2t, bq2, nullptr, Wq3, pout, 512, 1024, 2);
    reduce_head<<<64, 256, 0, stream>>>(pout, bq3, out);
}